// Round 1
// 166.843 us; speedup vs baseline: 1.0028x; 1.0028x over previous
//
#include <hip/hip_runtime.h>

#define BATCH 32
#define CH    84
#define NA    8400
#define KTOP  1000
#define GROUPS 2100          // NA/4 float4 groups per image
#define SLICES 33            // ceil(2100/64); 64 groups (256 anchors) per block
#define SLOT   32            // max candidates stored per slice (expected ~3.2)
#define MAXC   (SLICES*SLOT) // 1056 candidate slots per image
#define IOU_T 0.7f

// ---------------- Kernel A: candidate detection ----------------
// Channel-sliced waves for perfect coalescing: wave w covers a 20-channel band
// (w0:5..24 (+s0 ch4), w1:25..44, w2:45..64, w3:64..83; ch64 overlap is
// idempotent under max). Lane l covers anchor-group slice*64+l, so every load
// is 64 lanes x 16B contiguous = one 1KB transaction, 20 unrolled per wave.
// Cross-wave max via LDS; wave 0 (holding s0 in regs) tests + appends.
// valid anchor: s0 > 0.1 && s0 >= max(s1..s79)
// NEW: writes ALL SLOT entries per slice (sentinel score -1 for empties) so
// kernel B needs no counts array and can load slots unconditionally.
__global__ __launch_bounds__(256) void cand_kernel(const float* __restrict__ preds,
        float* __restrict__ cscore, int* __restrict__ cidx) {
    int b = blockIdx.x / SLICES;
    int slice = blockIdx.x - b * SLICES;
    int t = threadIdx.x;
    int w = t >> 6, l = t & 63;
    int g = slice * 64 + l;              // anchor group 0..2099
    bool active = g < GROUPS;

    __shared__ int lcount;
    __shared__ float4 red[3][64];        // waves 1..3 partial maxes
    __shared__ float lsc[256];
    __shared__ int   lix[256];
    if (t == 0) lcount = 0;

    const float* base = preds + (size_t)b * (CH * NA);
    float mx = -1.f, my = -1.f, mz = -1.f, mw = -1.f;
    float4 s0 = make_float4(-2.f, -2.f, -2.f, -2.f);
    if (active) {
        int c0 = (w < 3) ? (5 + 20 * w) : 64;          // 5..24,25..44,45..64,64..83
        const float* p = base + (size_t)c0 * NA + 4 * g;
        #pragma unroll
        for (int k = 0; k < 20; ++k, p += NA) {
            float4 v = *(const float4*)p;
            mx = fmaxf(mx, v.x); my = fmaxf(my, v.y);
            mz = fmaxf(mz, v.z); mw = fmaxf(mw, v.w);
        }
        if (w == 0) s0 = *(const float4*)(base + (size_t)4 * NA + 4 * g);
    }
    if (w > 0) red[w - 1][l] = make_float4(mx, my, mz, mw);
    __syncthreads();

    if (w == 0 && active) {
        #pragma unroll
        for (int ww = 0; ww < 3; ++ww) {
            float4 r = red[ww][l];
            mx = fmaxf(mx, r.x); my = fmaxf(my, r.y);
            mz = fmaxf(mz, r.z); mw = fmaxf(mw, r.w);
        }
        float s[4] = {s0.x, s0.y, s0.z, s0.w};
        float m[4] = {mx, my, mz, mw};
        #pragma unroll
        for (int k = 0; k < 4; ++k) {
            if (s[k] > 0.1f && s[k] >= m[k]) {
                int p_ = atomicAdd(&lcount, 1);     // LDS atomic only
                lsc[p_] = s[k];
                lix[p_] = 4 * g + k;
            }
        }
    }
    __syncthreads();
    int n = lcount; if (n > SLOT) n = SLOT;
    if (t < SLOT) {                                  // full slice write: poison-proof
        int o = b * MAXC + slice * SLOT + t;
        cscore[o] = (t < n) ? lsc[t] : -1.f;
        cidx[o]   = (t < n) ? lix[t] : 0;
    }
}

// broadcast lane src's register value to all lanes (~5cy vs ~120cy LDS read)
__device__ __forceinline__ float bcastf(float v, int src) {
    return __uint_as_float(__builtin_amdgcn_readlane(__float_as_uint(v), src));
}

// ---------------- wave-parallel greedy NMS scan ----------------
// One wave (64 lanes); lane owns rank-candidates k*64+lane, k<S, boxes in
// NAMED regs (compile-time indexed -> no scratch). Suppressor i's keep bit via
// __ballot; its box broadcast via v_readlane from the owning lane's registers
// (which = i>>6 is uniform -> cndmask-select the named reg, then readlane).
// pos[] maps rank -> raw compacted index (boxes stored in raw order).
template<int S>
__device__ unsigned int nms_scan(int n, int lane, const float4* bxy,
                                 const float* ars, const int* pos) {
    float ox1[S], oy1[S], ox2[S], oy2[S], oar[S];
    unsigned int keep = 0u;
    #pragma unroll
    for (int k = 0; k < S; ++k) {
        int c = k * 64 + lane;
        if (c < n) {
            int p = pos[c];
            float4 v = bxy[p];
            ox1[k] = v.x; oy1[k] = v.y; ox2[k] = v.z; oy2[k] = v.w;
            oar[k] = ars[p];
            keep |= (1u << k);
        } else {
            ox1[k] = 0.f; oy1[k] = 0.f; ox2[k] = -1.f; oy2[k] = -1.f; oar[k] = 0.f;
        }
    }
    for (int i = 0; i < n; ++i) {
        int which = i >> 6, src = i & 63;
        int mybit = (keep >> which) & 1;
        unsigned long long bal = __ballot(mybit);
        if ((bal >> src) & 1ull) {          // uniform branch: is candidate i kept?
            float sx1 = ox1[0], sy1 = oy1[0], sx2 = ox2[0], sy2 = oy2[0], sar = oar[0];
            #pragma unroll
            for (int q = 1; q < S; ++q)
                if (which == q) { sx1 = ox1[q]; sy1 = oy1[q]; sx2 = ox2[q]; sy2 = oy2[q]; sar = oar[q]; }
            float bix1 = bcastf(sx1, src), biy1 = bcastf(sy1, src);
            float bix2 = bcastf(sx2, src), biy2 = bcastf(sy2, src);
            float bia  = bcastf(sar, src);
            #pragma unroll
            for (int k = 0; k < S; ++k) {
                float lx = fmaxf(bix1, ox1[k]), ly = fmaxf(biy1, oy1[k]);
                float rx = fminf(bix2, ox2[k]), ry = fminf(biy2, oy2[k]);
                float iw = fmaxf(rx - lx, 0.0f), ih = fmaxf(ry - ly, 0.0f);
                float inter = iw * ih;
                float iou = inter / (bia + oar[k] - inter + 1e-7f);
                int c = k * 64 + lane;
                if (c > i && iou > IOU_T) keep &= ~(1u << k);
            }
        }
    }
    return keep;
}

// ---------------- Kernel B: compact + sort + NMS + output ----------------
// All global latency front-loaded: 5 slot loads/thread issued at entry,
// speculative box loads issued as soon as indices return (invalid slots read
// base[0] -> L1 hit, harmless). Ballot+popcount stream compaction replaces the
// counts round-trip and the serial prefix sum.
__global__ __launch_bounds__(256) void nms_kernel(const float* __restrict__ preds,
        const float* __restrict__ cscore, const int* __restrict__ cidx,
        float* __restrict__ out) {
    int b = blockIdx.x;
    int tid = threadIdx.x;
    int lane = tid & 63, w = tid >> 6;

    __shared__ unsigned long long masks[20];              // 5 rounds x 4 waves, t-order
    __shared__ int mbase[20];
    __shared__ int ntot_s;
    __shared__ float rs[MAXC]; __shared__ int ri[MAXC];   // compacted raw candidates
    __shared__ float4 bxy[MAXC];                          // raw-order boxes xyxy
    __shared__ float  ars[MAXC];                          // raw-order areas
    __shared__ float ss[MAXC];                            // rank-order scores
    __shared__ int   pos[MAXC];                           // rank -> raw index
    __shared__ unsigned int keepm[64];                    // per-lane keep bitmask

    const float* base = preds + (size_t)b * (CH * NA);
    const float* csb = cscore + (size_t)b * MAXC;
    const int*   cib = cidx   + (size_t)b * MAXC;

    // phase 1: issue all slot loads immediately (the only mandatory cold latency)
    float sc[5]; int ai[5];
    #pragma unroll
    for (int k = 0; k < 5; ++k) {
        int t = k * 256 + tid;
        bool in = t < MAXC;
        sc[k] = in ? csb[t] : -1.f;
        ai[k] = in ? cib[t] : 0;
    }
    // speculative box gather chained right behind the index loads
    float bx1[5], by1[5], bx2[5], by2[5], bar[5];
    #pragma unroll
    for (int k = 0; k < 5; ++k) {
        int a = ai[k];
        float cx = base[a], cy = base[NA + a];
        float ww = base[2 * NA + a], hh = base[3 * NA + a];
        float hx = ww * 0.5f, hy = hh * 0.5f;
        bx1[k] = cx - hx; by1[k] = cy - hy; bx2[k] = cx + hx; by2[k] = cy + hy;
        bar[k] = (bx2[k] - bx1[k]) * (by2[k] - by1[k]);
    }
    // ballot compaction: masks in raw t-order (k-major, wave-minor)
    unsigned long long bal[5];
    #pragma unroll
    for (int k = 0; k < 5; ++k) {
        bal[k] = __ballot(sc[k] > 0.f);
        if (lane == 0) masks[k * 4 + w] = bal[k];
    }
    __syncthreads();
    if (tid == 0) {                                       // 20-entry popc prefix, trivial
        int acc = 0;
        #pragma unroll
        for (int m = 0; m < 20; ++m) { mbase[m] = acc; acc += __popcll(masks[m]); }
        ntot_s = acc;
    }
    __syncthreads();
    unsigned long long lmask = (1ull << lane) - 1ull;
    #pragma unroll
    for (int k = 0; k < 5; ++k) {
        if (sc[k] > 0.f) {
            int dst = mbase[k * 4 + w] + __popcll(bal[k] & lmask);
            rs[dst] = sc[k]; ri[dst] = ai[k];
            bxy[dst] = make_float4(bx1[k], by1[k], bx2[k], by2[k]);
            ars[dst] = bar[k];
        }
    }
    __syncthreads();
    int n = __builtin_amdgcn_readfirstlane(ntot_s);

    // stable rank sort: rank = #{j : s_j > s_i || (s_j == s_i && idx_j < idx_i)}
    // boxes stay in raw order; pos[] carries the permutation.
    #pragma unroll
    for (int k = 0; k < 5; ++k) {
        int i = k * 256 + tid;
        if (i < n) {
            float si = rs[i]; int ii = ri[i];
            int r = 0;
            for (int j = 0; j < n; ++j) {
                float sj = rs[j]; int ij = ri[j];
                if (sj > si || (sj == si && ij < ii)) r++;
            }
            ss[r] = si; pos[r] = i;
        }
    }
    __syncthreads();

    if (tid < 64) {
        unsigned int kp;
        if (n <= 128)      kp = nms_scan<2>(n, tid, bxy, ars, pos);
        else if (n <= 256) kp = nms_scan<4>(n, tid, bxy, ars, pos);
        else if (n <= 512) kp = nms_scan<8>(n, tid, bxy, ars, pos);
        else               kp = nms_scan<17>(n, tid, bxy, ars, pos); // up to 1088 >= MAXC
        keepm[tid] = kp;
    }
    __syncthreads();

    // write all K rows as float4 (d_out poisoned -> zeros must be written too)
    float* ob = out + (size_t)b * (KTOP * 6);
    const float SCALEF = (float)(640.0 / 1920.0);
    for (int q = tid; q < (KTOP * 6) / 4; q += 256) {     // 1500 float4 per image
        float4 v;
        #pragma unroll
        for (int c = 0; c < 4; ++c) {
            int f = q * 4 + c;
            int r = f / 6, cc = f - r * 6;
            float val = 0.f;
            if (r < n && ((keepm[r & 63] >> (r >> 6)) & 1u)) {
                if (cc == 4) val = ss[r];
                else if (cc < 4) {
                    const float* bp = (const float*)&bxy[pos[r]];
                    val = bp[cc] / SCALEF;
                }
                // cc == 5: class 0 -> stays 0
            }
            ((float*)&v)[c] = val;
        }
        *(float4*)(ob + 4 * q) = v;
    }
}

extern "C" void kernel_launch(void* const* d_in, const int* in_sizes, int n_in,
                              void* d_out, int out_size, void* d_ws, size_t ws_size,
                              hipStream_t stream) {
    const float* preds = (const float*)d_in[0];
    float* out = (float*)d_out;

    // ws layout (all read locations are written by cand_kernel first -> no memset)
    float* cscore = (float*)d_ws;                                   // 32*1056 floats
    int*   cidx   = (int*)((char*)d_ws + (size_t)BATCH * MAXC * sizeof(float));

    cand_kernel<<<BATCH * SLICES, 256, 0, stream>>>(preds, cscore, cidx);
    nms_kernel<<<BATCH, 256, 0, stream>>>(preds, cscore, cidx, out);
}